// Round 3
// baseline (8553.584 us; speedup 1.0000x reference)
//
#include <hip/hip_runtime.h>
#include <cstdint>

// FPS: B=8, N=131072, NPOINT=1024.  Exact-index replication of the jax reference.
// State register-resident: 8 batches x 16 blocks x 1024 thr x 8 pts (x,y,z,mindist).
// Per round (ONE barrier, ONE global handoff, coords travel inside the posts):
//   update (no-FMA exact fp32) -> per-thread packed key
//   -> 6-level DPP wave max -> lane63 writes warr[wid] -> barrier
//   -> all lanes gather warr[lane&15] (LDS broadcast) + 4-level DPP group16
//      => every thread knows the block best
//   -> the unique thread whose own key == block best posts 4 self-tagged u64
//      slots from registers: [t|dist|~idx], [t|x], [t|y], [t|z]  (relaxed agent)
//   -> all waves spin on the 64 slots of the batch (lane i <-> slot i),
//      4-level DPP max over value slots (lanes 0-15), readlane coords.
// Packed u64: [t:15][fp32 dist bits:32][(~idx)&0x1FFFF:17] -> unsigned max ==
// (round, dist desc, idx asc) == np.argmax first-max tie-break. Self-tagged
// words need no fences; parity double-buffer bounds skew to 1 round; poisoned
// workspace tag (0x5555) never matches a live round.

constexpr int kB = 8;
constexpr int kN = 131072;
constexpr int kNpoint = 1024;
constexpr int kBlocksPerBatch = 16;
constexpr int kThreads = 1024;
constexpr int kPPT = 8;
constexpr int kPtsPerBlock = kThreads * kPPT;   // 8192
constexpr int kSlotsPerBatch = 64;              // 16 val + 16 x + 16 y + 16 z

__device__ __forceinline__ uint64_t u64max(uint64_t a, uint64_t b) {
    return a > b ? a : b;
}

template <int CTRL>
__device__ __forceinline__ uint64_t dpp_u64(uint64_t v) {
    int lo = __builtin_amdgcn_update_dpp(0, (int)(uint32_t)v, CTRL, 0xF, 0xF, false);
    int hi = __builtin_amdgcn_update_dpp(0, (int)(uint32_t)(v >> 32), CTRL, 0xF, 0xF, false);
    return ((uint64_t)(uint32_t)hi << 32) | (uint32_t)lo;
}

// Full-wave max; result valid in lane 63.
__device__ __forceinline__ uint64_t wave_max_to_lane63(uint64_t v) {
    v = u64max(v, dpp_u64<0x111>(v));  // row_shr:1
    v = u64max(v, dpp_u64<0x112>(v));  // row_shr:2
    v = u64max(v, dpp_u64<0x114>(v));  // row_shr:4
    v = u64max(v, dpp_u64<0x118>(v));  // row_shr:8
    v = u64max(v, dpp_u64<0x142>(v));  // row_bcast:15
    v = u64max(v, dpp_u64<0x143>(v));  // row_bcast:31
    return v;
}

// Max over each aligned group of 16 lanes (all lanes of the group get it).
__device__ __forceinline__ uint64_t group16_max(uint64_t v) {
    v = u64max(v, dpp_u64<0xB1>(v));   // quad_perm: xor 1
    v = u64max(v, dpp_u64<0x4E>(v));   // quad_perm: xor 2
    v = u64max(v, dpp_u64<0x141>(v));  // row_half_mirror
    v = u64max(v, dpp_u64<0x140>(v));  // row_mirror
    return v;
}

__global__ __launch_bounds__(kThreads, 4) void fps_kernel(
        const float* __restrict__ xyz, float* __restrict__ out,
        uint64_t* __restrict__ slots) {
    const int b    = blockIdx.x & 7;    // batch (round-robin XCD heuristic)
    const int blk  = blockIdx.x >> 3;   // block within batch, 0..15
    const int tid  = threadIdx.x;
    const int lane = tid & 63;

    const float* __restrict__ base = xyz + (size_t)b * kN * 3;

    float x[kPPT], y[kPPT], z[kPPT], md[kPPT];
#pragma unroll
    for (int j = 0; j < kPPT; ++j) {
        const int p = blk * kPtsPerBlock + j * kThreads + tid;
        x[j] = base[3 * p + 0];
        y[j] = base[3 * p + 1];
        z[j] = base[3 * p + 2];
        md[j] = __builtin_inff();
    }

    __shared__ uint64_t warr[kThreads / 64];  // per-wave bests

    // First sample is always point 0.
    float cx = base[0], cy = base[1], cz = base[2];
    if (blk == 0 && tid == 0) {
        float* o = out + (size_t)b * kNpoint * 3;
        o[0] = cx; o[1] = cy; o[2] = cz;
    }

    for (int t = 1; t < kNpoint; ++t) {
        // --- mindist update + per-thread argmax (exact fp32, no FMA) ---
        float bm = -1.0f;
        int bj = 0;
#pragma unroll
        for (int j = 0; j < kPPT; ++j) {
            const float dx = __fsub_rn(x[j], cx);
            const float dy = __fsub_rn(y[j], cy);
            const float dz = __fsub_rn(z[j], cz);
            const float d  = __fadd_rn(__fadd_rn(__fmul_rn(dx, dx), __fmul_rn(dy, dy)),
                                       __fmul_rn(dz, dz));
            const float m = fminf(md[j], d);
            md[j] = m;
            const bool g = m > bm;        // strict > keeps smallest j among ties
            bj = g ? j : bj;
            bm = g ? m : bm;
        }
        const uint32_t p = (uint32_t)(blk * kPtsPerBlock + bj * kThreads + tid);
        const uint64_t tt = (uint64_t)t << 49;
        const uint64_t pk = tt | ((uint64_t)__float_as_uint(bm) << 17) | ((~p) & 0x1FFFFu);

        // --- block max known to EVERY thread: wave ladder -> LDS -> group16 ---
        uint64_t wb = wave_max_to_lane63(pk);
        if (lane == 63) warr[tid >> 6] = wb;
        __syncthreads();  // the one barrier
        uint64_t bb = warr[lane & 15];   // broadcast gather (conflict-free)
        bb = group16_max(bb);            // all 64 lanes now hold the block best

        uint64_t* slotbuf = slots + ((size_t)(t & 1) * kB + b) * kSlotsPerBatch;

        // --- unique winning thread posts value + coords, all from registers ---
        if (pk == bb) {
            float wx = x[0], wy = y[0], wz = z[0];
#pragma unroll
            for (int j = 1; j < kPPT; ++j) {
                if (bj == j) { wx = x[j]; wy = y[j]; wz = z[j]; }
            }
            __hip_atomic_store(&slotbuf[blk], pk, __ATOMIC_RELAXED,
                               __HIP_MEMORY_SCOPE_AGENT);
            __hip_atomic_store(&slotbuf[16 + blk], tt | ((uint64_t)__float_as_uint(wx) << 17),
                               __ATOMIC_RELAXED, __HIP_MEMORY_SCOPE_AGENT);
            __hip_atomic_store(&slotbuf[32 + blk], tt | ((uint64_t)__float_as_uint(wy) << 17),
                               __ATOMIC_RELAXED, __HIP_MEMORY_SCOPE_AGENT);
            __hip_atomic_store(&slotbuf[48 + blk], tt | ((uint64_t)__float_as_uint(wz) << 17),
                               __ATOMIC_RELAXED, __HIP_MEMORY_SCOPE_AGENT);
        }

        // --- every wave spins on the 64 slots (lane i <-> slot i) ---
        uint64_t got = 0;
        bool need = true;
        while (__any(need)) {
            if (need) {
                uint64_t sv = __hip_atomic_load(&slotbuf[lane], __ATOMIC_RELAXED,
                                                __HIP_MEMORY_SCOPE_AGENT);
                if ((sv >> 49) == (uint64_t)t) { got = sv; need = false; }
            }
        }

        // value slots live in lanes 0-15; coords decoded via readlane
        uint64_t val = (lane < 16) ? got : 0;
        val = group16_max(val);
        const uint32_t blo = (uint32_t)__builtin_amdgcn_readfirstlane((int)(uint32_t)val);
        const uint32_t widx = 131071u - (blo & 0x1FFFFu);
        const int w = (int)(widx >> 13);          // winning block
        const uint32_t pay = (uint32_t)(got >> 17);
        cx = __uint_as_float((uint32_t)__builtin_amdgcn_readlane((int)pay, 16 + w));
        cy = __uint_as_float((uint32_t)__builtin_amdgcn_readlane((int)pay, 32 + w));
        cz = __uint_as_float((uint32_t)__builtin_amdgcn_readlane((int)pay, 48 + w));

        if (blk == 0 && tid == 0) {
            float* o = out + ((size_t)b * kNpoint + t) * 3;
            o[0] = cx; o[1] = cy; o[2] = cz;
        }
    }
}

extern "C" void kernel_launch(void* const* d_in, const int* in_sizes, int n_in,
                              void* d_out, int out_size, void* d_ws, size_t ws_size,
                              hipStream_t stream) {
    const float* xyz = (const float*)d_in[0];
    float* out = (float*)d_out;
    uint64_t* slots = (uint64_t*)d_ws;  // 2 * 8 * 64 u64 = 8 KiB used
    fps_kernel<<<dim3(kB * kBlocksPerBatch), dim3(kThreads), 0, stream>>>(xyz, out, slots);
}

// Round 4
// 4805.182 us; speedup vs baseline: 1.7801x; 1.7801x over previous
//
#include <hip/hip_runtime.h>
#include <cstdint>

// FPS: B=8, N=131072, NPOINT=1024.  Exact-index replication of the jax reference.
// State register-resident: 8 batches x 16 blocks x 1024 thr x 8 pts (x,y,z,mindist).
// R4 = R2 topology (16 value slots, 16-lane polls, coords re-read from xyz)
//      + parallel block combine (warr/group16, no serialized ds_atomic_max)
//      + direct post from the unique winning thread's registers (no tid0 LDS hop).
// Per round: update (no-FMA exact fp32) -> per-thread packed key
//   -> 6-level DPP wave max -> lane63 writes warr[wid] -> ONE barrier
//   -> all lanes gather warr[lane&15] + 4-level DPP group16 => block best everywhere
//   -> thread with pk==blockbest posts slot[blk] (relaxed agent, self-tagged)
//   -> all waves spin on 16 slots (lanes 0-15 only), group16, readfirstlane,
//      winner coords re-read from read-only xyz (L2-hit).
// Packed u64: [t:15][fp32 dist bits:32][(~idx)&0x1FFFF:17] -> unsigned max ==
// (round, dist desc, idx asc) == np.argmax first-max tie-break. Self-tagged
// single-u64 payloads need no fences; parity double-buffer bounds skew to one
// round; 0xAA-poisoned workspace tag (0x5555) never matches a live round.

constexpr int kB = 8;
constexpr int kN = 131072;
constexpr int kNpoint = 1024;
constexpr int kBlocksPerBatch = 16;
constexpr int kThreads = 1024;
constexpr int kPPT = 8;
constexpr int kPtsPerBlock = kThreads * kPPT;  // 8192

__device__ __forceinline__ uint64_t u64max(uint64_t a, uint64_t b) {
    return a > b ? a : b;
}

template <int CTRL>
__device__ __forceinline__ uint64_t dpp_u64(uint64_t v) {
    int lo = __builtin_amdgcn_update_dpp(0, (int)(uint32_t)v, CTRL, 0xF, 0xF, false);
    int hi = __builtin_amdgcn_update_dpp(0, (int)(uint32_t)(v >> 32), CTRL, 0xF, 0xF, false);
    return ((uint64_t)(uint32_t)hi << 32) | (uint32_t)lo;
}

// Full-wave max; result valid in lane 63.
__device__ __forceinline__ uint64_t wave_max_to_lane63(uint64_t v) {
    v = u64max(v, dpp_u64<0x111>(v));  // row_shr:1
    v = u64max(v, dpp_u64<0x112>(v));  // row_shr:2
    v = u64max(v, dpp_u64<0x114>(v));  // row_shr:4
    v = u64max(v, dpp_u64<0x118>(v));  // row_shr:8
    v = u64max(v, dpp_u64<0x142>(v));  // row_bcast:15
    v = u64max(v, dpp_u64<0x143>(v));  // row_bcast:31
    return v;
}

// Max over each aligned group of 16 lanes (all lanes of the group get it).
__device__ __forceinline__ uint64_t group16_max(uint64_t v) {
    v = u64max(v, dpp_u64<0xB1>(v));   // quad_perm: xor 1
    v = u64max(v, dpp_u64<0x4E>(v));   // quad_perm: xor 2
    v = u64max(v, dpp_u64<0x141>(v));  // row_half_mirror
    v = u64max(v, dpp_u64<0x140>(v));  // row_mirror
    return v;
}

__global__ __launch_bounds__(kThreads, 4) void fps_kernel(
        const float* __restrict__ xyz, float* __restrict__ out,
        uint64_t* __restrict__ slots) {
    const int b    = blockIdx.x & 7;    // batch (round-robin XCD heuristic)
    const int blk  = blockIdx.x >> 3;   // block within batch, 0..15
    const int tid  = threadIdx.x;
    const int lane = tid & 63;

    const float* __restrict__ base = xyz + (size_t)b * kN * 3;

    float x[kPPT], y[kPPT], z[kPPT], md[kPPT];
#pragma unroll
    for (int j = 0; j < kPPT; ++j) {
        const int p = blk * kPtsPerBlock + j * kThreads + tid;
        x[j] = base[3 * p + 0];
        y[j] = base[3 * p + 1];
        z[j] = base[3 * p + 2];
        md[j] = __builtin_inff();
    }

    __shared__ uint64_t warr[kThreads / 64];  // per-wave bests

    // First sample is always point 0.
    float cx = base[0], cy = base[1], cz = base[2];
    if (blk == 0 && tid == 0) {
        float* o = out + (size_t)b * kNpoint * 3;
        o[0] = cx; o[1] = cy; o[2] = cz;
    }

    for (int t = 1; t < kNpoint; ++t) {
        // --- mindist update + per-thread argmax (exact fp32, no FMA) ---
        float bm = -1.0f;
        int bj = 0;
#pragma unroll
        for (int j = 0; j < kPPT; ++j) {
            const float dx = __fsub_rn(x[j], cx);
            const float dy = __fsub_rn(y[j], cy);
            const float dz = __fsub_rn(z[j], cz);
            const float d  = __fadd_rn(__fadd_rn(__fmul_rn(dx, dx), __fmul_rn(dy, dy)),
                                       __fmul_rn(dz, dz));
            const float m = fminf(md[j], d);
            md[j] = m;
            const bool g = m > bm;        // strict > keeps smallest j among ties
            bj = g ? j : bj;
            bm = g ? m : bm;
        }
        const uint32_t p = (uint32_t)(blk * kPtsPerBlock + bj * kThreads + tid);
        const uint64_t pk = ((uint64_t)t << 49) |
                            ((uint64_t)__float_as_uint(bm) << 17) | ((~p) & 0x1FFFFu);

        // --- block best known to EVERY thread: ladder -> LDS -> gather -> group16 ---
        uint64_t wb = wave_max_to_lane63(pk);
        if (lane == 63) warr[tid >> 6] = wb;
        __syncthreads();  // the one barrier
        uint64_t bb = warr[lane & 15];   // LDS broadcast gather (conflict-free)
        bb = group16_max(bb);            // all 64 lanes hold the block best

        uint64_t* slotbuf = slots + ((size_t)(t & 1) * kB + b) * kBlocksPerBatch;

        // --- the unique winning thread posts straight from registers ---
        if (pk == bb) {
            __hip_atomic_store(&slotbuf[blk], pk, __ATOMIC_RELAXED,
                               __HIP_MEMORY_SCOPE_AGENT);
        }

        // --- every wave spins on the 16 slots (lanes 0-15 only) ---
        uint64_t got = 0;
        bool need = lane < kBlocksPerBatch;
        while (__any(need)) {
            if (need) {
                uint64_t sv = __hip_atomic_load(&slotbuf[lane], __ATOMIC_RELAXED,
                                                __HIP_MEMORY_SCOPE_AGENT);
                if ((sv >> 49) == (uint64_t)t) { got = sv; need = false; }
            }
        }
        got = group16_max(got);  // lanes 0-15 hold the batch winner

        const uint32_t blo = (uint32_t)__builtin_amdgcn_readfirstlane((int)(uint32_t)got);
        const uint32_t widx = 131071u - (blo & 0x1FFFFu);
        cx = base[3 * (size_t)widx + 0];
        cy = base[3 * (size_t)widx + 1];
        cz = base[3 * (size_t)widx + 2];
        if (blk == 0 && tid == 0) {
            float* o = out + ((size_t)b * kNpoint + t) * 3;
            o[0] = cx; o[1] = cy; o[2] = cz;
        }
    }
}

extern "C" void kernel_launch(void* const* d_in, const int* in_sizes, int n_in,
                              void* d_out, int out_size, void* d_ws, size_t ws_size,
                              hipStream_t stream) {
    const float* xyz = (const float*)d_in[0];
    float* out = (float*)d_out;
    uint64_t* slots = (uint64_t*)d_ws;  // 2 * 8 * 16 u64 = 2 KiB used
    fps_kernel<<<dim3(kB * kBlocksPerBatch), dim3(kThreads), 0, stream>>>(xyz, out, slots);
}

// Round 5
// 2034.012 us; speedup vs baseline: 4.2053x; 2.3624x over previous
//
#include <hip/hip_runtime.h>
#include <cstdint>

// FPS: B=8, N=131072, NPOINT=1024.  Exact-index replication of the jax reference.
// R5 = EXACT R2 structure (fastest measured: 2027 us) + s_sleep(1) poll backoff.
//   R2 structure: update (no-FMA exact fp32) -> per-thread packed key
//   -> 6-level DPP wave max -> lane63 ds_atomic_max into tag-packed LDS u64
//   -> ONE barrier -> tid0 posts LDS value to global slot (relaxed agent store)
//   -> all waves spin on 16 slots (lanes 0-15), NOW with s_sleep(1) after a
//      failed poll (cuts poll-fabric congestion ~8x; detection quantized +<=64cyc)
//   -> 4-level DPP group16, readfirstlane, winner coords re-read from xyz (L2).
// Packed u64: [t:15][fp32 dist bits:32][(~idx)&0x1FFFF:17] -> unsigned max ==
// (round, dist desc, idx asc) == np.argmax first-max tie-break. Self-tagged
// single-u64 payloads need no fences; parity double-buffer bounds skew to one
// round; 0xAA-poisoned workspace tag never matches a live round tag.

constexpr int kB = 8;
constexpr int kN = 131072;
constexpr int kNpoint = 1024;
constexpr int kBlocksPerBatch = 16;
constexpr int kThreads = 1024;
constexpr int kPPT = 8;
constexpr int kPtsPerBlock = kThreads * kPPT;  // 8192

__device__ __forceinline__ uint64_t u64max(uint64_t a, uint64_t b) {
    return a > b ? a : b;
}

template <int CTRL>
__device__ __forceinline__ uint64_t dpp_u64(uint64_t v) {
    int lo = __builtin_amdgcn_update_dpp(0, (int)(uint32_t)v, CTRL, 0xF, 0xF, false);
    int hi = __builtin_amdgcn_update_dpp(0, (int)(uint32_t)(v >> 32), CTRL, 0xF, 0xF, false);
    return ((uint64_t)(uint32_t)hi << 32) | (uint32_t)lo;
}

// Full-wave max; result valid in lane 63.
__device__ __forceinline__ uint64_t wave_max_to_lane63(uint64_t v) {
    v = u64max(v, dpp_u64<0x111>(v));  // row_shr:1
    v = u64max(v, dpp_u64<0x112>(v));  // row_shr:2
    v = u64max(v, dpp_u64<0x114>(v));  // row_shr:4
    v = u64max(v, dpp_u64<0x118>(v));  // row_shr:8
    v = u64max(v, dpp_u64<0x142>(v));  // row_bcast:15
    v = u64max(v, dpp_u64<0x143>(v));  // row_bcast:31
    return v;
}

// Max over each aligned group of 16 lanes (all lanes of the group get it).
__device__ __forceinline__ uint64_t group16_max(uint64_t v) {
    v = u64max(v, dpp_u64<0xB1>(v));   // quad_perm: xor 1
    v = u64max(v, dpp_u64<0x4E>(v));   // quad_perm: xor 2
    v = u64max(v, dpp_u64<0x141>(v));  // row_half_mirror
    v = u64max(v, dpp_u64<0x140>(v));  // row_mirror
    return v;
}

__global__ __launch_bounds__(kThreads, 4) void fps_kernel(
        const float* __restrict__ xyz, float* __restrict__ out,
        uint64_t* __restrict__ slots) {
    const int b    = blockIdx.x & 7;    // batch (round-robin XCD heuristic)
    const int blk  = blockIdx.x >> 3;   // block within batch, 0..15
    const int tid  = threadIdx.x;
    const int lane = tid & 63;

    const float* __restrict__ base = xyz + (size_t)b * kN * 3;

    float x[kPPT], y[kPPT], z[kPPT], md[kPPT];
#pragma unroll
    for (int j = 0; j < kPPT; ++j) {
        const int p = blk * kPtsPerBlock + j * kThreads + tid;
        x[j] = base[3 * p + 0];
        y[j] = base[3 * p + 1];
        z[j] = base[3 * p + 2];
        md[j] = __builtin_inff();
    }

    __shared__ uint64_t lbest[2];
    if (tid == 0) { lbest[0] = 0; lbest[1] = 0; }

    // First sample is always point 0.
    float cx = base[0], cy = base[1], cz = base[2];
    if (blk == 0 && tid == 0) {
        float* o = out + (size_t)b * kNpoint * 3;
        o[0] = cx; o[1] = cy; o[2] = cz;
    }
    __syncthreads();  // lbest init visible

    for (int t = 1; t < kNpoint; ++t) {
        // --- mindist update + per-thread argmax (exact fp32, no FMA) ---
        float bm = -1.0f;
        int bj = 0;
#pragma unroll
        for (int j = 0; j < kPPT; ++j) {
            const float dx = __fsub_rn(x[j], cx);
            const float dy = __fsub_rn(y[j], cy);
            const float dz = __fsub_rn(z[j], cz);
            const float d  = __fadd_rn(__fadd_rn(__fmul_rn(dx, dx), __fmul_rn(dy, dy)),
                                       __fmul_rn(dz, dz));
            const float m = fminf(md[j], d);
            md[j] = m;
            const bool g = m > bm;        // strict > keeps smallest j among ties
            bj = g ? j : bj;
            bm = g ? m : bm;
        }
        const uint32_t p = (uint32_t)(blk * kPtsPerBlock + bj * kThreads + tid);
        uint64_t pk = ((uint64_t)t << 49) |
                      ((uint64_t)__float_as_uint(bm) << 17) | ((~p) & 0x1FFFFu);

        // --- wave max -> lane 63 -> LDS atomic max (tag-packed, parity dbuf) ---
        pk = wave_max_to_lane63(pk);
        if (lane == 63) {
            __hip_atomic_fetch_max(&lbest[t & 1], pk, __ATOMIC_RELAXED,
                                   __HIP_MEMORY_SCOPE_WORKGROUP);
        }
        __syncthreads();  // the one barrier: block best complete in LDS

        uint64_t* slotbuf = slots + ((size_t)(t & 1) * kB + b) * kBlocksPerBatch;
        if (tid == 0) {
            __hip_atomic_store(&slotbuf[blk], lbest[t & 1], __ATOMIC_RELAXED,
                               __HIP_MEMORY_SCOPE_AGENT);
        }

        // --- every wave spins on the 16 slots, throttled with s_sleep ---
        uint64_t got = 0;
        bool need = lane < kBlocksPerBatch;
        while (__any(need)) {
            if (need) {
                uint64_t sv = __hip_atomic_load(&slotbuf[lane], __ATOMIC_RELAXED,
                                                __HIP_MEMORY_SCOPE_AGENT);
                if ((sv >> 49) == (uint64_t)t) { got = sv; need = false; }
            }
            if (__any(need)) __builtin_amdgcn_s_sleep(1);  // ~64 cyc backoff
        }
        got = group16_max(got);  // lanes 0-15 hold the batch winner

        const uint32_t blo = (uint32_t)__builtin_amdgcn_readfirstlane((int)(uint32_t)got);
        const uint32_t widx = 131071u - (blo & 0x1FFFFu);
        cx = base[3 * (size_t)widx + 0];
        cy = base[3 * (size_t)widx + 1];
        cz = base[3 * (size_t)widx + 2];
        if (blk == 0 && tid == 0) {
            float* o = out + ((size_t)b * kNpoint + t) * 3;
            o[0] = cx; o[1] = cy; o[2] = cz;
        }
    }
}

extern "C" void kernel_launch(void* const* d_in, const int* in_sizes, int n_in,
                              void* d_out, int out_size, void* d_ws, size_t ws_size,
                              hipStream_t stream) {
    const float* xyz = (const float*)d_in[0];
    float* out = (float*)d_out;
    uint64_t* slots = (uint64_t*)d_ws;  // 2 * 8 * 16 u64 = 2 KiB used
    fps_kernel<<<dim3(kB * kBlocksPerBatch), dim3(kThreads), 0, stream>>>(xyz, out, slots);
}